// Round 1
// baseline (199.433 us; speedup 1.0000x reference)
//
#include <hip/hip_runtime.h>
#include <math.h>

#define NA   21
#define NM   64
#define ND   210
#define DK2  216          // K2 iterates d in 27 chunks of 8 (rows 210..215 are zero)
#define DPAD 256          // storage rows for d (210..255 zero)
#define NT   8192

#define QC 0.22360679774997896f   // sqrt(5)/10
#define KE 0.016666666666666666f  // 5/(3*sig^2) = 5/300

// ---- workspace layout (float offsets) ----
#define O_QXST 0u                        // [DPAD][NM]      16384
#define O_QXTT 16384u                    // [DPAD][NT]      2097152
#define O_JXT  (O_QXTT + 2097152u)       // [DPAD][NT]      2097152
#define O_NT   (O_JXT + 2097152u)        // [NT]            8192
#define O_CJ   (O_NT + 8192u)            // [NT]            8192
#define O_NX   (O_CJ + 8192u)            // [NM]            64
#define O_W1   (O_NX + 64u)              // [NM][NT]        524288
#define O_E1   (O_W1 + 524288u)          // [NM][NT]        524288
#define O_ES   (O_E1 + 524288u)          // [NM]            64
#define O_WA   (O_ES + 64u)              // [NM]            64
#define O_AB   (O_WA + 64u)              // [2][NM][DPAD]   32768
#define ZERO_N (64u + 64u + 2u*NM*DPAD)  // EsAcc+Wacc+ABacc contiguous = 32896

__device__ __forceinline__ void d_to_ij(int d, int& i, int& j) {
    int ii = (int)((1.0f + sqrtf(1.0f + 8.0f * (float)d)) * 0.5f);
    while (ii * (ii - 1) / 2 > d) --ii;
    while ((ii + 1) * ii / 2 <= d) ++ii;
    i = ii;
    j = d - ii * (ii - 1) / 2;
}

__global__ void k_zero(float* __restrict__ p, int n) {
    int i = blockIdx.x * 256 + threadIdx.x;
    if (i < n) p[i] = 0.0f;
}

// grid 64 (m) x 256 thr: qxsT[d][m] = q/dist(pair d), zero-padded rows; nx[m] = sum (q*xs)^2
__global__ void k_geom(const float* __restrict__ Rs, float* __restrict__ qxsT,
                       float* __restrict__ nx) {
    int m = blockIdx.x, tid = threadIdx.x;
    __shared__ float R[NA][3];
    __shared__ float red[256];
    if (tid < NA * 3) ((float*)R)[tid] = Rs[m * NA * 3 + tid];
    __syncthreads();
    float local = 0.0f;
    for (int d = tid; d < DPAD; d += 256) {
        float v = 0.0f;
        if (d < ND) {
            int i, j; d_to_ij(d, i, j);
            float dx = R[i][0] - R[j][0];
            float dy = R[i][1] - R[j][1];
            float dz = R[i][2] - R[j][2];
            float dist = sqrtf(dx * dx + dy * dy + dz * dz);
            v = QC / dist;
        }
        qxsT[d * NM + m] = v;
        local += v * v;
    }
    red[tid] = local;
    __syncthreads();
    for (int s = 128; s > 0; s >>= 1) {
        if (tid < s) red[tid] += red[tid + s];
        __syncthreads();
    }
    if (tid == 0) nx[m] = red[0];
}

// grid 128 (t-tiles of 64) x 256 thr: dst[d][t] = scale*src[t][d], rows d>=210 zero
__global__ void k_transpose(const float* __restrict__ src, float* __restrict__ dst,
                            float scale) {
    int t0 = blockIdx.x * 64, tid = threadIdx.x;
    __shared__ float tile[64][ND + 1];
    for (int idx = tid; idx < 64 * ND; idx += 256) {
        int t = idx / ND, d = idx - t * ND;
        tile[t][d] = src[(size_t)(t0 + t) * ND + d];
    }
    __syncthreads();
    for (int idx = tid; idx < DPAD * 64; idx += 256) {
        int d = idx >> 6, t = idx & 63;
        float v = (d < ND) ? scale * tile[t][d] : 0.0f;
        dst[(size_t)d * NT + t0 + t] = v;
    }
}

// grid 32 x 256: nt[t] = ||q xt||^2, cJ[t] = (q xt) . Jx
__global__ void k_pert(const float* __restrict__ qxtT, const float* __restrict__ JxT,
                       float* __restrict__ nt, float* __restrict__ cJ) {
    int t = blockIdx.x * 256 + threadIdx.x;
    float sn = 0.0f, sc = 0.0f;
    for (int d = 0; d < ND; ++d) {
        float a = qxtT[(size_t)d * NT + t];
        float b = JxT[(size_t)d * NT + t];
        sn = fmaf(a, a, sn);
        sc = fmaf(a, b, sc);
    }
    nt[t] = sn;
    cJ[t] = sc;
}

// Stage 1: grid 256 (t-tiles of 32) x 256 thr. Block tile 64m x 32t, thread 2m x 4t.
// C1 = qxs.qxt, C2 = qxs.Jx over d; fused exp epilogue -> w1, e1, Es/W atomics.
__global__ __launch_bounds__(256) void k_stage1(
    const float* __restrict__ qxsT, const float* __restrict__ qxtT,
    const float* __restrict__ JxT, const float* __restrict__ nt,
    const float* __restrict__ cJ, const float* __restrict__ nx,
    float* __restrict__ w1, float* __restrict__ e1,
    float* __restrict__ EsAcc, float* __restrict__ Wacc) {
    const int t0 = blockIdx.x * 32;
    const int tid = threadIdx.x;
    const int mloc = (tid >> 3) * 2;   // m base (0..62)
    const int tloc = (tid & 7) * 4;    // t base within tile (0..28)

    __shared__ float As[8][64];
    __shared__ float B1s[8][32];
    __shared__ float B2s[8][32];
    __shared__ float red[64][8];

    float c1[2][4] = {};
    float c2[2][4] = {};

    const int ad = tid >> 6, am = tid & 63;   // A staging
    const int br = tid >> 5, bc = tid & 31;   // B staging

    for (int dk = 0; dk < DK2; dk += 8) {
        As[ad][am]     = qxsT[(dk + ad) * NM + am];
        As[ad + 4][am] = qxsT[(dk + ad + 4) * NM + am];
        B1s[br][bc] = qxtT[(size_t)(dk + br) * NT + t0 + bc];
        B2s[br][bc] = JxT[(size_t)(dk + br) * NT + t0 + bc];
        __syncthreads();
#pragma unroll
        for (int dd = 0; dd < 8; ++dd) {
            float a0 = As[dd][mloc];
            float a1 = As[dd][mloc + 1];
            const float4 b1 = *(const float4*)&B1s[dd][tloc];
            const float4 b2 = *(const float4*)&B2s[dd][tloc];
            float bb1[4] = {b1.x, b1.y, b1.z, b1.w};
            float bb2[4] = {b2.x, b2.y, b2.z, b2.w};
#pragma unroll
            for (int j = 0; j < 4; ++j) {
                c1[0][j] = fmaf(a0, bb1[j], c1[0][j]);
                c1[1][j] = fmaf(a1, bb1[j], c1[1][j]);
                c2[0][j] = fmaf(a0, bb2[j], c2[0][j]);
                c2[1][j] = fmaf(a1, bb2[j], c2[1][j]);
            }
        }
        __syncthreads();
    }

    float esl[2] = {0.0f, 0.0f}, wl[2] = {0.0f, 0.0f};
#pragma unroll
    for (int i = 0; i < 2; ++i) {
        int m = mloc + i;
        float nxm = nx[m];
#pragma unroll
        for (int j = 0; j < 4; ++j) {
            int t = t0 + tloc + j;
            float sq = nxm - 2.0f * c1[i][j] + nt[t];
            sq = fmaxf(sq, 0.0f);
            float xd = sqrtf(sq);
            float e = KE * expf(-xd);
            float dotv = c2[i][j] - cJ[t];
            float w1v = e * dotv;
            float e1v = e * (1.0f + xd);
            w1[(size_t)m * NT + t] = w1v;
            e1[(size_t)m * NT + t] = e1v;
            esl[i] += e1v * dotv;
            wl[i] += w1v;
        }
    }
    red[mloc][tid & 7] = esl[0];
    red[mloc + 1][tid & 7] = esl[1];
    __syncthreads();
    if (tid < 64) {
        float s = 0.0f;
#pragma unroll
        for (int k = 0; k < 8; ++k) s += red[tid][k];
        atomicAdd(&EsAcc[tid], s);
    }
    __syncthreads();
    red[mloc][tid & 7] = wl[0];
    red[mloc + 1][tid & 7] = wl[1];
    __syncthreads();
    if (tid < 64) {
        float s = 0.0f;
#pragma unroll
        for (int k = 0; k < 8; ++k) s += red[tid][k];
        atomicAdd(&Wacc[tid], s);
    }
}

// Stage 2: grid (4 d-tiles, 64 k-splits) x 256 thr. Block 64m x 64d, K-chunk 128 t.
// A[m,d] += sum_t w1*qxt ; B[m,d] += sum_t e1*Jx  (atomic across k-splits)
__global__ __launch_bounds__(256) void k_stage2(
    const float* __restrict__ w1, const float* __restrict__ e1,
    const float* __restrict__ qxtT, const float* __restrict__ JxT,
    float* __restrict__ ABacc) {
    const int d0 = blockIdx.x * 64;
    const int k0 = blockIdx.y * 128;
    const int tid = threadIdx.x;
    const int dloc = (tid & 15) * 4;   // d within tile
    const int mloc = (tid >> 4) * 4;   // m

    __shared__ float Aw[32][68];
    __shared__ float Ae[32][68];
    __shared__ float B1s[32][68];
    __shared__ float B2s[32][68];

    float accA[4][4] = {};
    float accB[4][4] = {};

    const int st = tid & 31, sr0 = tid >> 5;

    for (int kt = 0; kt < 128; kt += 32) {
        const size_t kbase = (size_t)(k0 + kt);
#pragma unroll
        for (int r = sr0; r < 64; r += 8) {
            Aw[st][r]  = w1[(size_t)r * NT + kbase + st];
            Ae[st][r]  = e1[(size_t)r * NT + kbase + st];
            B1s[st][r] = qxtT[(size_t)(d0 + r) * NT + kbase + st];
            B2s[st][r] = JxT[(size_t)(d0 + r) * NT + kbase + st];
        }
        __syncthreads();
#pragma unroll 4
        for (int t = 0; t < 32; ++t) {
            const float4 aw = *(const float4*)&Aw[t][mloc];
            const float4 ae = *(const float4*)&Ae[t][mloc];
            const float4 b1 = *(const float4*)&B1s[t][dloc];
            const float4 b2 = *(const float4*)&B2s[t][dloc];
            float awv[4] = {aw.x, aw.y, aw.z, aw.w};
            float aev[4] = {ae.x, ae.y, ae.z, ae.w};
            float b1v[4] = {b1.x, b1.y, b1.z, b1.w};
            float b2v[4] = {b2.x, b2.y, b2.z, b2.w};
#pragma unroll
            for (int i = 0; i < 4; ++i)
#pragma unroll
                for (int j = 0; j < 4; ++j) {
                    accA[i][j] = fmaf(awv[i], b1v[j], accA[i][j]);
                    accB[i][j] = fmaf(aev[i], b2v[j], accB[i][j]);
                }
        }
        __syncthreads();
    }
#pragma unroll
    for (int i = 0; i < 4; ++i)
#pragma unroll
        for (int j = 0; j < 4; ++j) {
            int m = mloc + i, d = d0 + dloc + j;
            atomicAdd(&ABacc[(size_t)m * DPAD + d], accA[i][j]);
            atomicAdd(&ABacc[(size_t)NM * DPAD + (size_t)m * DPAD + d], accB[i][j]);
        }
}

// grid 64 (m) x 256: scatter Fs_x to symmetric 21x21 / dist^3, contract with diffs; Es
__global__ void k_final(const float* __restrict__ Rs, const float* __restrict__ qxsT,
                        const float* __restrict__ ABacc, const float* __restrict__ EsAcc,
                        const float* __restrict__ Wacc, float* __restrict__ out) {
    int m = blockIdx.x, tid = threadIdx.x;
    __shared__ float R[NA][3];
    __shared__ float Ff[NA][NA];
    if (tid < NA * 3) ((float*)R)[tid] = Rs[m * NA * 3 + tid];
    if (tid < NA) Ff[tid][tid] = 0.0f;
    __syncthreads();
    if (tid < ND) {
        int i, j; d_to_ij(tid, i, j);
        float dx = R[i][0] - R[j][0];
        float dy = R[i][1] - R[j][1];
        float dz = R[i][2] - R[j][2];
        float dist2 = dx * dx + dy * dy + dz * dz;
        float dist = sqrtf(dist2);
        float fsx = qxsT[tid * NM + m] * Wacc[m]
                  - ABacc[(size_t)m * DPAD + tid]
                  - ABacc[(size_t)NM * DPAD + (size_t)m * DPAD + tid];
        float f = fsx / (dist2 * dist);
        Ff[i][j] = f;
        Ff[j][i] = f;
    }
    __syncthreads();
    if (tid < NA * 3) {
        int a = tid / 3, c = tid % 3;
        float s = 0.0f;
        for (int b = 0; b < NA; ++b) {
            if (b == a) continue;
            s += Ff[a][b] * (R[a][c] - R[b][c]);
        }
        out[NM + m * NA * 3 + tid] = s;
    }
    if (tid == 0) out[m] = EsAcc[m] / QC;   // STD=1, C=0
}

extern "C" void kernel_launch(void* const* d_in, const int* in_sizes, int n_in,
                              void* d_out, int out_size, void* d_ws, size_t ws_size,
                              hipStream_t stream) {
    const float* Rs = (const float*)d_in[0];
    const float* xs_train = (const float*)d_in[1];
    const float* Jx_alphas = (const float*)d_in[2];
    float* out = (float*)d_out;
    float* ws = (float*)d_ws;

    float* qxsT = ws + O_QXST;
    float* qxtT = ws + O_QXTT;
    float* JxT  = ws + O_JXT;
    float* nt   = ws + O_NT;
    float* cJ   = ws + O_CJ;
    float* nx   = ws + O_NX;
    float* w1   = ws + O_W1;
    float* e1   = ws + O_E1;
    float* EsAcc = ws + O_ES;
    float* Wacc  = ws + O_WA;
    float* ABacc = ws + O_AB;

    k_zero<<<(ZERO_N + 255) / 256, 256, 0, stream>>>(EsAcc, (int)ZERO_N);
    k_geom<<<NM, 256, 0, stream>>>(Rs, qxsT, nx);
    k_transpose<<<NT / 64, 256, 0, stream>>>(xs_train, qxtT, QC);
    k_transpose<<<NT / 64, 256, 0, stream>>>(Jx_alphas, JxT, 1.0f);
    k_pert<<<NT / 256, 256, 0, stream>>>(qxtT, JxT, nt, cJ);
    k_stage1<<<NT / 32, 256, 0, stream>>>(qxsT, qxtT, JxT, nt, cJ, nx, w1, e1, EsAcc, Wacc);
    k_stage2<<<dim3(4, 64), 256, 0, stream>>>(w1, e1, qxtT, JxT, ABacc);
    k_final<<<NM, 256, 0, stream>>>(Rs, qxsT, ABacc, EsAcc, Wacc, out);
}